// Round 8
// baseline (83.733 us; speedup 1.0000x reference)
//
#include <hip/hip_runtime.h>

// GCN layer: out[i,:] = relu( dinv[i] * sum_{e: dst=i} dinv[src_e] * x[src_e,:] )
// dinv[i] = indeg>0 ? indeg^-1/2 : 0
//
// Primary path (4 dispatches, ZERO global atomics):
//   K1 k_count_conv: blocks (range r, chunk c): LDS histogram of chunk-c dsts in
//      node-range r -> hist16[c][d] (16-bit, coalesced). Extra blocks: x fp32->bf16.
//   K2 k_base: per node d: exclusive prefix of hist16[:][d] over chunks (in place),
//      deg[d], dinv[d].
//   K3 k_place: re-scan chunk, LDS counters seeded with hist16[c][d] bases,
//      ofs = ldsAtomicAdd -> edges[d*cap+ofs] = src. Scattered stores only.
//   K4 k_gather_bf16: 16-lane group per node, unroll 4, fused dinv scale + relu.
// Fallbacks: direct atomic path (R5), last-resort atomic scatter.

#define RCHUNKS 64   // edge chunks
#define NRANGES 4    // node ranges
#define MAXRNG 13000 // LDS counter capacity per range (52KB < 64KB static LDS)

__device__ __forceinline__ int detect_is64(const unsigned int* w) {
    const int t = threadIdx.x & 63;
    unsigned long long m = __ballot(w[2 * t + 1] != 0u);
    return m == 0ull ? 1 : 0;
}

__device__ __forceinline__ int load_idx(const void* p, long long i, int is64) {
    return is64 ? (int)((const long long*)p)[i] : ((const int*)p)[i];
}

__device__ __forceinline__ unsigned short f2bf(float f) {
    unsigned u = __float_as_uint(f);
    unsigned r = (u + 0x7fffu + ((u >> 16) & 1u)) >> 16;  // RNE; inputs finite
    return (unsigned short)r;
}

__global__ void __launch_bounds__(256) k_zero(int4* p, int n4) {
    const int stride = gridDim.x * blockDim.x;
    for (int i = blockIdx.x * blockDim.x + threadIdx.x; i < n4; i += stride)
        p[i] = make_int4(0, 0, 0, 0);
}

// ---------------- primary path ----------------

// K1: LDS histogram per (range, chunk) || bf16 convert.
__global__ void __launch_bounds__(256) k_count_conv(const void* ei,
                                                    unsigned short* __restrict__ hist16,
                                                    const float* __restrict__ x,
                                                    unsigned short* __restrict__ xb,
                                                    int E, int n, int CH, int RNG, int nconv) {
    const int bid = blockIdx.x;
    if (bid < RCHUNKS * NRANGES) {
        const int c = bid >> 2;
        const int r = bid & 3;
        const int lo = r * RNG;
        const int hi = min(lo + RNG, n);
        const int width = hi - lo;
        __shared__ int cnt[MAXRNG];
        for (int i = threadIdx.x; i < width; i += 256) cnt[i] = 0;
        __syncthreads();
        const int is64 = detect_is64((const unsigned int*)ei);
        const int e0 = c * CH;
        const int e1 = min(e0 + CH, E);
        for (int e = e0 + threadIdx.x; e < e1; e += 256) {
            int d = load_idx(ei, (long long)E + e, is64);
            if (d >= lo && d < hi) atomicAdd(&cnt[d - lo], 1);
        }
        __syncthreads();
        unsigned short* hrow = hist16 + (size_t)c * n + lo;
        for (int i = threadIdx.x; i < width; i += 256) hrow[i] = (unsigned short)cnt[i];
    } else if (xb) {
        const long long tid = (long long)(bid - RCHUNKS * NRANGES) * 256 + threadIdx.x;
        if (tid < nconv) {
            const long long i = tid * 8;
            float4 a = *(const float4*)(x + i);
            float4 b = *(const float4*)(x + i + 4);
            union { unsigned short us[8]; uint4 v; } o;
            o.us[0] = f2bf(a.x); o.us[1] = f2bf(a.y); o.us[2] = f2bf(a.z); o.us[3] = f2bf(a.w);
            o.us[4] = f2bf(b.x); o.us[5] = f2bf(b.y); o.us[6] = f2bf(b.z); o.us[7] = f2bf(b.w);
            *(uint4*)(xb + i) = o.v;
        }
    }
}

// K2: per-node exclusive prefix across chunks (in place) + deg + dinv.
__global__ void __launch_bounds__(256) k_base(unsigned short* __restrict__ hist16,
                                              int* __restrict__ deg,
                                              float* __restrict__ dinv, int n) {
    const int d = blockIdx.x * blockDim.x + threadIdx.x;
    if (d >= n) return;
    int acc = 0;
    #pragma unroll 8
    for (int c = 0; c < RCHUNKS; ++c) {
        size_t idx = (size_t)c * n + d;
        int v = hist16[idx];
        hist16[idx] = (unsigned short)acc;
        acc += v;
    }
    deg[d] = acc;
    dinv[d] = (acc > 0) ? rsqrtf((float)acc) : 0.f;
}

// K3: place edges; LDS counters seeded with per-chunk bases; no global atomics.
__global__ void __launch_bounds__(256) k_place(const void* ei,
                                               const unsigned short* __restrict__ hist16,
                                               int* __restrict__ edges,
                                               int E, int n, int CH, int RNG, int cap) {
    const int bid = blockIdx.x;
    const int c = bid >> 2;
    const int r = bid & 3;
    const int lo = r * RNG;
    const int hi = min(lo + RNG, n);
    const int width = hi - lo;
    __shared__ int cnt[MAXRNG];
    const unsigned short* hrow = hist16 + (size_t)c * n + lo;
    for (int i = threadIdx.x; i < width; i += 256) cnt[i] = hrow[i];
    __syncthreads();
    const int is64 = detect_is64((const unsigned int*)ei);
    const int e0 = c * CH;
    const int e1 = min(e0 + CH, E);
    for (int e = e0 + threadIdx.x; e < e1; e += 256) {
        int d = load_idx(ei, (long long)E + e, is64);
        if (d >= lo && d < hi) {
            int s = load_idx(ei, e, is64);
            int ofs = atomicAdd(&cnt[d - lo], 1);
            if (ofs < cap) edges[(long long)d * cap + ofs] = s;
        }
    }
}

// K4: gather, bf16 rows: 16-lane group per node, lane owns 8 features (16B loads).
__global__ void __launch_bounds__(256) k_gather_bf16(const unsigned short* __restrict__ xb,
                                                     const int* __restrict__ edges,
                                                     const int* __restrict__ deg,
                                                     const float* __restrict__ dinv,
                                                     float* __restrict__ out, int n, int cap) {
    const int node = blockIdx.x * 16 + (threadIdx.x >> 4);
    if (node >= n) return;
    const int lane = threadIdx.x & 15;
    const int m = min(deg[node], cap);
    const int* eb = edges + (long long)node * cap;
    float acc[8] = {0.f, 0.f, 0.f, 0.f, 0.f, 0.f, 0.f, 0.f};

    auto accum = [&](int s, float w) {
        uint4 v = ((const uint4*)(xb + (long long)s * 128))[lane];
        acc[0] += w * __uint_as_float(v.x << 16);
        acc[1] += w * __uint_as_float(v.x & 0xffff0000u);
        acc[2] += w * __uint_as_float(v.y << 16);
        acc[3] += w * __uint_as_float(v.y & 0xffff0000u);
        acc[4] += w * __uint_as_float(v.z << 16);
        acc[5] += w * __uint_as_float(v.z & 0xffff0000u);
        acc[6] += w * __uint_as_float(v.w << 16);
        acc[7] += w * __uint_as_float(v.w & 0xffff0000u);
    };

    int e = 0;
    for (; e + 3 < m; e += 4) {
        int s0 = eb[e], s1 = eb[e + 1], s2 = eb[e + 2], s3 = eb[e + 3];
        float w0 = dinv[s0], w1 = dinv[s1], w2 = dinv[s2], w3 = dinv[s3];
        accum(s0, w0); accum(s1, w1); accum(s2, w2); accum(s3, w3);
    }
    for (; e < m; ++e) {
        int s0 = eb[e];
        accum(s0, dinv[s0]);
    }
    const float dd = dinv[node];
    float4 o0, o1;
    o0.x = fmaxf(dd * acc[0], 0.f); o0.y = fmaxf(dd * acc[1], 0.f);
    o0.z = fmaxf(dd * acc[2], 0.f); o0.w = fmaxf(dd * acc[3], 0.f);
    o1.x = fmaxf(dd * acc[4], 0.f); o1.y = fmaxf(dd * acc[5], 0.f);
    o1.z = fmaxf(dd * acc[6], 0.f); o1.w = fmaxf(dd * acc[7], 0.f);
    float4* op = (float4*)(out + (long long)node * 128);
    op[lane * 2] = o0;
    op[lane * 2 + 1] = o1;
}

// Gather, fp32 rows (fallback when ws can't hold xb).
__global__ void __launch_bounds__(256) k_gather_f32(const float* __restrict__ x,
                                                    const int* __restrict__ edges,
                                                    const int* __restrict__ deg,
                                                    const float* __restrict__ dinv,
                                                    float* __restrict__ out, int n, int cap) {
    const int node = blockIdx.x * 8 + (threadIdx.x >> 5);
    if (node >= n) return;
    const int lane = threadIdx.x & 31;
    const int m = min(deg[node], cap);
    const int* eb = edges + (long long)node * cap;
    float ax = 0.f, ay = 0.f, az = 0.f, aw = 0.f;
    int e = 0;
    for (; e + 3 < m; e += 4) {
        int s0 = eb[e], s1 = eb[e + 1], s2 = eb[e + 2], s3 = eb[e + 3];
        float w0 = dinv[s0], w1 = dinv[s1], w2 = dinv[s2], w3 = dinv[s3];
        float4 v0 = *(const float4*)(x + (long long)s0 * 128 + lane * 4);
        float4 v1 = *(const float4*)(x + (long long)s1 * 128 + lane * 4);
        float4 v2 = *(const float4*)(x + (long long)s2 * 128 + lane * 4);
        float4 v3 = *(const float4*)(x + (long long)s3 * 128 + lane * 4);
        ax += w0 * v0.x + w1 * v1.x + w2 * v2.x + w3 * v3.x;
        ay += w0 * v0.y + w1 * v1.y + w2 * v2.y + w3 * v3.y;
        az += w0 * v0.z + w1 * v1.z + w2 * v2.z + w3 * v3.z;
        aw += w0 * v0.w + w1 * v1.w + w2 * v2.w + w3 * v3.w;
    }
    for (; e < m; ++e) {
        int s0 = eb[e];
        float w0 = dinv[s0];
        float4 v0 = *(const float4*)(x + (long long)s0 * 128 + lane * 4);
        ax += w0 * v0.x; ay += w0 * v0.y; az += w0 * v0.z; aw += w0 * v0.w;
    }
    const float dd = dinv[node];
    float4 rr;
    rr.x = fmaxf(dd * ax, 0.f); rr.y = fmaxf(dd * ay, 0.f);
    rr.z = fmaxf(dd * az, 0.f); rr.w = fmaxf(dd * aw, 0.f);
    *(float4*)(out + (long long)node * 128 + lane * 4) = rr;
}

// ---------------- direct fallback (smaller ws) ----------------

__global__ void k_fill_direct(const void* ei, int* cnt, int* edges, int E, int cap) {
    const int is64 = detect_is64((const unsigned int*)ei);
    const int stride = gridDim.x * blockDim.x;
    for (int e = blockIdx.x * blockDim.x + threadIdx.x; e < E; e += stride) {
        int s = load_idx(ei, e, is64);
        int d = load_idx(ei, (long long)E + e, is64);
        int pos = atomicAdd(&cnt[d], 1);
        if (pos < cap) edges[(long long)d * cap + pos] = s;
    }
}

__global__ void __launch_bounds__(256) k_gather_pad(const float* __restrict__ x,
                                                    const int* __restrict__ edges,
                                                    const int* __restrict__ cnt,
                                                    float* __restrict__ out, int n, int cap) {
    const int node = blockIdx.x * 8 + (threadIdx.x >> 5);
    if (node >= n) return;
    const int lane = threadIdx.x & 31;
    const int m0 = cnt[node];
    const int m = min(m0, cap);
    const int* eb = edges + (long long)node * cap;
    float ax = 0.f, ay = 0.f, az = 0.f, aw = 0.f;
    int e = 0;
    for (; e + 3 < m; e += 4) {
        int s0 = eb[e], s1 = eb[e + 1], s2 = eb[e + 2], s3 = eb[e + 3];
        int c0 = cnt[s0], c1 = cnt[s1], c2 = cnt[s2], c3 = cnt[s3];
        float4 v0 = *(const float4*)(x + (long long)s0 * 128 + lane * 4);
        float4 v1 = *(const float4*)(x + (long long)s1 * 128 + lane * 4);
        float4 v2 = *(const float4*)(x + (long long)s2 * 128 + lane * 4);
        float4 v3 = *(const float4*)(x + (long long)s3 * 128 + lane * 4);
        float w0 = c0 > 0 ? rsqrtf((float)c0) : 0.f;
        float w1 = c1 > 0 ? rsqrtf((float)c1) : 0.f;
        float w2 = c2 > 0 ? rsqrtf((float)c2) : 0.f;
        float w3 = c3 > 0 ? rsqrtf((float)c3) : 0.f;
        ax += w0 * v0.x + w1 * v1.x + w2 * v2.x + w3 * v3.x;
        ay += w0 * v0.y + w1 * v1.y + w2 * v2.y + w3 * v3.y;
        az += w0 * v0.z + w1 * v1.z + w2 * v2.z + w3 * v3.z;
        aw += w0 * v0.w + w1 * v1.w + w2 * v2.w + w3 * v3.w;
    }
    for (; e < m; ++e) {
        int s0 = eb[e];
        int c0 = cnt[s0];
        float4 v0 = *(const float4*)(x + (long long)s0 * 128 + lane * 4);
        float w0 = c0 > 0 ? rsqrtf((float)c0) : 0.f;
        ax += w0 * v0.x; ay += w0 * v0.y; az += w0 * v0.z; aw += w0 * v0.w;
    }
    const float dd = m0 > 0 ? rsqrtf((float)m0) : 0.f;
    float4 rr;
    rr.x = fmaxf(dd * ax, 0.f); rr.y = fmaxf(dd * ay, 0.f);
    rr.z = fmaxf(dd * az, 0.f); rr.w = fmaxf(dd * aw, 0.f);
    *(float4*)(out + (long long)node * 128 + lane * 4) = rr;
}

// ---------------- last-resort atomic scatter (near-zero ws) ----------------

__global__ void k_deg_simple(const void* ei, float* deg, int E) {
    const int is64 = detect_is64((const unsigned int*)ei);
    const int stride = gridDim.x * blockDim.x;
    for (int e = blockIdx.x * blockDim.x + threadIdx.x; e < E; e += stride)
        atomicAdd(&deg[load_idx(ei, (long long)E + e, is64)], 1.0f);
}
__global__ void k_dinv_simple(float* deg, int n) {
    int i = blockIdx.x * blockDim.x + threadIdx.x;
    if (i < n) { float d = deg[i]; deg[i] = d > 0.f ? rsqrtf(d) : 0.f; }
}
__global__ void k_scatter_atomic(const float* __restrict__ x, const void* ei,
                                 const float* __restrict__ dinv, float* out, int E) {
    const int is64 = detect_is64((const unsigned int*)ei);
    const int lane = threadIdx.x & 31;
    const int eslot = threadIdx.x >> 5;
    const int stride = gridDim.x * 8;
    for (int e = blockIdx.x * 8 + eslot; e < E; e += stride) {
        int s = load_idx(ei, e, is64);
        int d = load_idx(ei, (long long)E + e, is64);
        float norm = dinv[s] * dinv[d];
        float4 v = ((const float4*)(x + (long long)s * 128))[lane];
        float* o = out + (long long)d * 128 + lane * 4;
        atomicAdd(o + 0, norm * v.x); atomicAdd(o + 1, norm * v.y);
        atomicAdd(o + 2, norm * v.z); atomicAdd(o + 3, norm * v.w);
    }
}
__global__ void k_relu4(float4* out, int n4) {
    const int stride = gridDim.x * blockDim.x;
    for (int i = blockIdx.x * blockDim.x + threadIdx.x; i < n4; i += stride) {
        float4 v = out[i];
        v.x = fmaxf(v.x, 0.f); v.y = fmaxf(v.y, 0.f);
        v.z = fmaxf(v.z, 0.f); v.w = fmaxf(v.w, 0.f);
        out[i] = v;
    }
}

extern "C" void kernel_launch(void* const* d_in, const int* in_sizes, int n_in,
                              void* d_out, int out_size, void* d_ws, size_t ws_size,
                              hipStream_t stream) {
    const float* x = (const float*)d_in[0];
    const void* ei = d_in[1];
    const int D = 128;
    const int n = in_sizes[0] / D;   // 50000
    const int E = in_sizes[1] / 2;   // 600000

    char* ws = (char*)d_ws;
    size_t off = 0;
    auto alloc = [&](size_t bytes) {
        char* p = ws + off;
        off += (bytes + 255) & ~(size_t)255;
        return p;
    };
    auto al = [](size_t b) { return (b + 255) & ~(size_t)255; };

    const int RNG = (n + NRANGES - 1) / NRANGES;        // 12500
    const int CH  = (E + RCHUNKS - 1) / RCHUNKS;        // 9375
    const size_t szHist = al((size_t)RCHUNKS * n * 2);  // 6.4MB
    const size_t szDeg  = al((size_t)n * 4);
    const size_t szDinv = al((size_t)n * 4);
    const size_t szXb   = al((size_t)n * D * 2);
    auto needH = [&](int cap, bool bf16) {
        return szHist + szDeg + szDinv + al((size_t)n * cap * 4) + (bf16 ? szXb : 0);
    };

    if (RNG <= MAXRNG) {
        int cap = 0; bool bf16 = false; bool planH = false;
        if      (ws_size >= needH(64, true))  { cap = 64; bf16 = true;  planH = true; }
        else if (ws_size >= needH(48, true))  { cap = 48; bf16 = true;  planH = true; }
        else if (ws_size >= needH(64, false)) { cap = 64; bf16 = false; planH = true; }
        else if (ws_size >= needH(48, false)) { cap = 48; bf16 = false; planH = true; }

        if (planH) {
            unsigned short* hist16 = (unsigned short*)alloc((size_t)RCHUNKS * n * 2);
            int*   deg  = (int*)alloc((size_t)n * 4);
            float* dinv = (float*)alloc((size_t)n * 4);
            int*   edges = (int*)alloc((size_t)n * cap * 4);
            unsigned short* xb = bf16 ? (unsigned short*)alloc((size_t)n * D * 2) : nullptr;

            const int nconv = n * D / 8;  // 800000
            const int grid1 = RCHUNKS * NRANGES + (bf16 ? (nconv + 255) / 256 : 0);
            k_count_conv<<<grid1, 256, 0, stream>>>(ei, hist16, x, xb, E, n, CH, RNG, nconv);
            k_base<<<(n + 255) / 256, 256, 0, stream>>>(hist16, deg, dinv, n);
            k_place<<<RCHUNKS * NRANGES, 256, 0, stream>>>(ei, hist16, edges, E, n, CH, RNG, cap);
            if (bf16) {
                k_gather_bf16<<<(n + 15) / 16, 256, 0, stream>>>(xb, edges, deg, dinv,
                                                                 (float*)d_out, n, cap);
            } else {
                k_gather_f32<<<(n + 7) / 8, 256, 0, stream>>>(x, edges, deg, dinv,
                                                              (float*)d_out, n, cap);
            }
            return;
        }
    }

    // direct fallback
    auto needD = [&](int c) { return al((size_t)n * 4) + al((size_t)n * c * 4); };
    if (ws_size >= needD(48)) {
        int c = (ws_size >= needD(64)) ? 64 : 48;
        int* cnt   = (int*)alloc((size_t)n * 4);
        int* edges = (int*)alloc((size_t)n * c * 4);
        k_zero<<<(n / 4 + 255) / 256, 256, 0, stream>>>((int4*)cnt, n / 4);
        k_fill_direct<<<2048, 256, 0, stream>>>(ei, cnt, edges, E, c);
        k_gather_pad<<<(n + 7) / 8, 256, 0, stream>>>(x, edges, cnt, (float*)d_out, n, c);
        return;
    }

    // last resort: atomic scatter
    float* deg = (float*)alloc((size_t)n * 4);
    hipMemsetAsync(deg, 0, (size_t)n * sizeof(float), stream);
    hipMemsetAsync(d_out, 0, (size_t)out_size * sizeof(float), stream);
    k_deg_simple<<<2048, 256, 0, stream>>>(ei, deg, E);
    k_dinv_simple<<<(n + 255) / 256, 256, 0, stream>>>(deg, n);
    k_scatter_atomic<<<4096, 256, 0, stream>>>(x, ei, deg, (float*)d_out, E);
    k_relu4<<<2048, 256, 0, stream>>>((float4*)d_out, out_size / 4);
}

// Round 9
// 59.459 us; speedup vs baseline: 1.4083x; 1.4083x over previous
//
#include <hip/hip_runtime.h>

// GCN layer: out[i,:] = relu( dinv[i] * sum_{e: dst=i} dinv[src_e] * x[src_e,:] )
// dinv[i] = indeg>0 ? indeg^-1/2 : 0
//
// Primary path (4 dispatches, coalesced edge reordering):
//   K0 k_zero_cur: zero per-bucket cursors (391 ints).
//   K1 k_sort_conv: 128 blocks: LDS counting-sort of a ~4.7k-edge chunk by
//      128-node bucket (word=(d<<16)|s), ONE global atomic per (block,bucket),
//      then LINEAR coalesced write of the sorted chunk into bucket segments.
//      Extra blocks: x fp32->bf16 convert (RNE).
//   K2 k_dinv: per bucket: LDS histogram of dlocal -> dinv (no deg array).
//   K3 k_gather: per EIGHTH-bucket (16 nodes, 3128 blocks): filter + 16-way LDS
//      counting sort, then 16-lane-group/node register accum over bf16 rows,
//      fused dinv scale + relu, coalesced out writes.
// Fallbacks: direct padded-atomic path; last-resort atomic scatter.

#define SORTB    128   // sort blocks
#define CHUNKMAX 4704  // max edges per sort block (LDS-sized)
#define NBP      512   // padded bucket count (supports n <= 65536)
#define BCAP     2048  // bucket capacity (words)
#define GCAP     512   // per-eighth-bucket capacity in gather

__device__ __forceinline__ int detect_is64(const unsigned int* w) {
    const int t = threadIdx.x & 63;
    unsigned long long m = __ballot(w[2 * t + 1] != 0u);
    return m == 0ull ? 1 : 0;
}

__device__ __forceinline__ int load_idx(const void* p, long long i, int is64) {
    return is64 ? (int)((const long long*)p)[i] : ((const int*)p)[i];
}

__device__ __forceinline__ unsigned short f2bf(float f) {
    unsigned u = __float_as_uint(f);
    unsigned r = (u + 0x7fffu + ((u >> 16) & 1u)) >> 16;  // RNE; inputs finite
    return (unsigned short)r;
}

__global__ void k_zero_cur(int* cursor, int nb) {
    for (int i = threadIdx.x; i < nb; i += blockDim.x) cursor[i] = 0;
}

__global__ void __launch_bounds__(256) k_zero(int4* p, int n4) {
    const int stride = gridDim.x * blockDim.x;
    for (int i = blockIdx.x * blockDim.x + threadIdx.x; i < n4; i += stride)
        p[i] = make_int4(0, 0, 0, 0);
}

// ---------------- primary path ----------------

// K1: per-chunk LDS counting sort by bucket (d>>7) + coalesced segment write,
//     fused with fp32->bf16 convert on extra blocks.
__global__ void __launch_bounds__(256) k_sort_conv(const void* ei, int* cursor,
                                                   unsigned int* __restrict__ buckets,
                                                   const float* __restrict__ x,
                                                   unsigned short* __restrict__ xb,
                                                   int E, int n, int CH, int nconv) {
    const int bid = blockIdx.x;
    if (bid < SORTB) {
        __shared__ unsigned int raw[CHUNKMAX];
        __shared__ unsigned int srt[CHUNKMAX];
        __shared__ int hist[NBP];
        __shared__ int lbase[NBP];
        __shared__ int gbase[NBP];
        __shared__ int lcur[NBP];
        const int t = threadIdx.x;
        for (int i = t; i < NBP; i += 256) hist[i] = 0;
        __syncthreads();
        const int is64 = detect_is64((const unsigned int*)ei);
        const int e0 = bid * CH;
        const int e1 = min(e0 + CH, E);
        const int nch = e1 - e0;
        for (int i = t; i < nch; i += 256) {
            const long long e = e0 + i;
            int s = load_idx(ei, e, is64);
            int d = load_idx(ei, (long long)E + e, is64);
            unsigned w = ((unsigned)d << 16) | (unsigned)s;
            raw[i] = w;
            atomicAdd(&hist[d >> 7], 1);
        }
        __syncthreads();
        // exclusive scan of hist[0..NBP) by wave 0 (64 lanes x 8 elems)
        if (t < 64) {
            const int base = t * 8;
            int v[8];
            int sum = 0;
            #pragma unroll
            for (int k = 0; k < 8; ++k) { v[k] = hist[base + k]; sum += v[k]; }
            int pre = sum;
            for (int off = 1; off < 64; off <<= 1) {
                int u = __shfl_up(pre, off);
                if (t >= off) pre += u;
            }
            pre -= sum;  // exclusive
            #pragma unroll
            for (int k = 0; k < 8; ++k) { lbase[base + k] = pre; pre += v[k]; }
        }
        __syncthreads();
        // one global atomic per non-empty (block, bucket)
        for (int b = t; b < NBP; b += 256) {
            const int c = hist[b];
            gbase[b] = c ? atomicAdd(&cursor[b], c) : 0;
            lcur[b] = lbase[b];
        }
        __syncthreads();
        // scatter into sorted LDS order
        for (int i = t; i < nch; i += 256) {
            const unsigned w = raw[i];
            const int p = atomicAdd(&lcur[w >> 23], 1);
            srt[p] = w;
        }
        __syncthreads();
        // linear (coalesced) write: segment-contiguous global positions
        for (int i = t; i < nch; i += 256) {
            const unsigned w = srt[i];
            const int b = w >> 23;
            const int g = gbase[b] + (i - lbase[b]);
            if (g < BCAP) buckets[(size_t)b * BCAP + g] = w;
        }
    } else if (xb) {
        const long long tid = (long long)(bid - SORTB) * 256 + threadIdx.x;
        if (tid < nconv) {
            const long long i = tid * 8;
            float4 a = *(const float4*)(x + i);
            float4 b = *(const float4*)(x + i + 4);
            union { unsigned short us[8]; uint4 v; } o;
            o.us[0] = f2bf(a.x); o.us[1] = f2bf(a.y); o.us[2] = f2bf(a.z); o.us[3] = f2bf(a.w);
            o.us[4] = f2bf(b.x); o.us[5] = f2bf(b.y); o.us[6] = f2bf(b.z); o.us[7] = f2bf(b.w);
            *(uint4*)(xb + i) = o.v;
        }
    }
}

// K2: per-bucket LDS histogram -> dinv.
__global__ void __launch_bounds__(128) k_dinv(const int* __restrict__ cursor,
                                              const unsigned int* __restrict__ buckets,
                                              float* __restrict__ dinv, int n) {
    const int b = blockIdx.x;
    __shared__ int h[128];
    const int t = threadIdx.x;
    h[t] = 0;
    __syncthreads();
    const int len = min(cursor[b], BCAP);
    const unsigned int* bb = buckets + (size_t)b * BCAP;
    for (int i = t; i < len; i += 128) atomicAdd(&h[(bb[i] >> 16) & 127], 1);
    __syncthreads();
    const int node = b * 128 + t;
    if (node < n) {
        const int c = h[t];
        dinv[node] = (c > 0) ? rsqrtf((float)c) : 0.f;
    }
}

// K3: gather per eighth-bucket (16 nodes). Filter + 16-way counting sort in LDS,
//     then register accum per node over bf16 rows.
__global__ void __launch_bounds__(256) k_gather(const unsigned int* __restrict__ buckets,
                                                const int* __restrict__ cursor,
                                                const unsigned short* __restrict__ xb,
                                                const float* __restrict__ dinv,
                                                float* __restrict__ out, int n) {
    const int b = blockIdx.x >> 3;
    const int oct = blockIdx.x & 7;
    __shared__ unsigned int kept[GCAP];
    __shared__ unsigned int srt[GCAP];
    __shared__ int h[16], st[17], lc[16];
    __shared__ int nk;
    const int t = threadIdx.x;
    if (t == 0) nk = 0;
    if (t < 16) h[t] = 0;
    __syncthreads();
    const int len = min(cursor[b], BCAP);
    const unsigned int* bb = buckets + (size_t)b * BCAP;
    for (int i = t; i < len; i += 256) {
        const unsigned w = bb[i];
        const int dl = (w >> 16) & 127;
        if ((dl >> 4) == oct) {
            const int p = atomicAdd(&nk, 1);
            if (p < GCAP) { kept[p] = w; atomicAdd(&h[dl & 15], 1); }
        }
    }
    __syncthreads();
    if (t < 16) {
        const int v = h[t];
        int pre = v;
        for (int off = 1; off < 16; off <<= 1) {
            int u = __shfl_up(pre, off);
            if (t >= off) pre += u;
        }
        pre -= v;
        st[t] = pre; lc[t] = pre;
        if (t == 15) st[16] = pre + v;
    }
    __syncthreads();
    const int nkk = min(nk, GCAP);
    for (int i = t; i < nkk; i += 256) {
        const unsigned w = kept[i];
        const int p = atomicAdd(&lc[(w >> 16) & 15], 1);
        srt[p] = w;
    }
    __syncthreads();
    const int g = t >> 4;
    const int lane = t & 15;
    const int node = b * 128 + oct * 16 + g;
    if (node >= n) return;
    int e = st[g];
    const int eend = st[g + 1];
    float acc[8] = {0.f, 0.f, 0.f, 0.f, 0.f, 0.f, 0.f, 0.f};

    auto accum = [&](int s, float w) {
        uint4 v = ((const uint4*)(xb + (size_t)s * 128))[lane];
        acc[0] += w * __uint_as_float(v.x << 16);
        acc[1] += w * __uint_as_float(v.x & 0xffff0000u);
        acc[2] += w * __uint_as_float(v.y << 16);
        acc[3] += w * __uint_as_float(v.y & 0xffff0000u);
        acc[4] += w * __uint_as_float(v.z << 16);
        acc[5] += w * __uint_as_float(v.z & 0xffff0000u);
        acc[6] += w * __uint_as_float(v.w << 16);
        acc[7] += w * __uint_as_float(v.w & 0xffff0000u);
    };

    for (; e + 3 < eend; e += 4) {
        const int s0 = srt[e] & 0xffff,     s1 = srt[e + 1] & 0xffff;
        const int s2 = srt[e + 2] & 0xffff, s3 = srt[e + 3] & 0xffff;
        const float w0 = dinv[s0], w1 = dinv[s1], w2 = dinv[s2], w3 = dinv[s3];
        accum(s0, w0); accum(s1, w1); accum(s2, w2); accum(s3, w3);
    }
    for (; e < eend; ++e) {
        const int s0 = srt[e] & 0xffff;
        accum(s0, dinv[s0]);
    }
    const float dd = dinv[node];
    float4 o0, o1;
    o0.x = fmaxf(dd * acc[0], 0.f); o0.y = fmaxf(dd * acc[1], 0.f);
    o0.z = fmaxf(dd * acc[2], 0.f); o0.w = fmaxf(dd * acc[3], 0.f);
    o1.x = fmaxf(dd * acc[4], 0.f); o1.y = fmaxf(dd * acc[5], 0.f);
    o1.z = fmaxf(dd * acc[6], 0.f); o1.w = fmaxf(dd * acc[7], 0.f);
    float4* op = (float4*)(out + (size_t)node * 128);
    op[lane * 2] = o0;
    op[lane * 2 + 1] = o1;
}

// ---------------- direct fallback (smaller ws) ----------------

__global__ void k_fill_direct(const void* ei, int* cnt, int* edges, int E, int cap) {
    const int is64 = detect_is64((const unsigned int*)ei);
    const int stride = gridDim.x * blockDim.x;
    for (int e = blockIdx.x * blockDim.x + threadIdx.x; e < E; e += stride) {
        int s = load_idx(ei, e, is64);
        int d = load_idx(ei, (long long)E + e, is64);
        int pos = atomicAdd(&cnt[d], 1);
        if (pos < cap) edges[(long long)d * cap + pos] = s;
    }
}

__global__ void __launch_bounds__(256) k_gather_pad(const float* __restrict__ x,
                                                    const int* __restrict__ edges,
                                                    const int* __restrict__ cnt,
                                                    float* __restrict__ out, int n, int cap) {
    const int node = blockIdx.x * 8 + (threadIdx.x >> 5);
    if (node >= n) return;
    const int lane = threadIdx.x & 31;
    const int m0 = cnt[node];
    const int m = min(m0, cap);
    const int* eb = edges + (long long)node * cap;
    float ax = 0.f, ay = 0.f, az = 0.f, aw = 0.f;
    int e = 0;
    for (; e + 3 < m; e += 4) {
        int s0 = eb[e], s1 = eb[e + 1], s2 = eb[e + 2], s3 = eb[e + 3];
        int c0 = cnt[s0], c1 = cnt[s1], c2 = cnt[s2], c3 = cnt[s3];
        float4 v0 = *(const float4*)(x + (long long)s0 * 128 + lane * 4);
        float4 v1 = *(const float4*)(x + (long long)s1 * 128 + lane * 4);
        float4 v2 = *(const float4*)(x + (long long)s2 * 128 + lane * 4);
        float4 v3 = *(const float4*)(x + (long long)s3 * 128 + lane * 4);
        float w0 = c0 > 0 ? rsqrtf((float)c0) : 0.f;
        float w1 = c1 > 0 ? rsqrtf((float)c1) : 0.f;
        float w2 = c2 > 0 ? rsqrtf((float)c2) : 0.f;
        float w3 = c3 > 0 ? rsqrtf((float)c3) : 0.f;
        ax += w0 * v0.x + w1 * v1.x + w2 * v2.x + w3 * v3.x;
        ay += w0 * v0.y + w1 * v1.y + w2 * v2.y + w3 * v3.y;
        az += w0 * v0.z + w1 * v1.z + w2 * v2.z + w3 * v3.z;
        aw += w0 * v0.w + w1 * v1.w + w2 * v2.w + w3 * v3.w;
    }
    for (; e < m; ++e) {
        int s0 = eb[e];
        int c0 = cnt[s0];
        float4 v0 = *(const float4*)(x + (long long)s0 * 128 + lane * 4);
        float w0 = c0 > 0 ? rsqrtf((float)c0) : 0.f;
        ax += w0 * v0.x; ay += w0 * v0.y; az += w0 * v0.z; aw += w0 * v0.w;
    }
    const float dd = m0 > 0 ? rsqrtf((float)m0) : 0.f;
    float4 rr;
    rr.x = fmaxf(dd * ax, 0.f); rr.y = fmaxf(dd * ay, 0.f);
    rr.z = fmaxf(dd * az, 0.f); rr.w = fmaxf(dd * aw, 0.f);
    *(float4*)(out + (long long)node * 128 + lane * 4) = rr;
}

// ---------------- last-resort atomic scatter (near-zero ws) ----------------

__global__ void k_deg_simple(const void* ei, float* deg, int E) {
    const int is64 = detect_is64((const unsigned int*)ei);
    const int stride = gridDim.x * blockDim.x;
    for (int e = blockIdx.x * blockDim.x + threadIdx.x; e < E; e += stride)
        atomicAdd(&deg[load_idx(ei, (long long)E + e, is64)], 1.0f);
}
__global__ void k_dinv_simple(float* deg, int n) {
    int i = blockIdx.x * blockDim.x + threadIdx.x;
    if (i < n) { float d = deg[i]; deg[i] = d > 0.f ? rsqrtf(d) : 0.f; }
}
__global__ void k_scatter_atomic(const float* __restrict__ x, const void* ei,
                                 const float* __restrict__ dinv, float* out, int E) {
    const int is64 = detect_is64((const unsigned int*)ei);
    const int lane = threadIdx.x & 31;
    const int eslot = threadIdx.x >> 5;
    const int stride = gridDim.x * 8;
    for (int e = blockIdx.x * 8 + eslot; e < E; e += stride) {
        int s = load_idx(ei, e, is64);
        int d = load_idx(ei, (long long)E + e, is64);
        float norm = dinv[s] * dinv[d];
        float4 v = ((const float4*)(x + (long long)s * 128))[lane];
        float* o = out + (long long)d * 128 + lane * 4;
        atomicAdd(o + 0, norm * v.x); atomicAdd(o + 1, norm * v.y);
        atomicAdd(o + 2, norm * v.z); atomicAdd(o + 3, norm * v.w);
    }
}
__global__ void k_relu4(float4* out, int n4) {
    const int stride = gridDim.x * blockDim.x;
    for (int i = blockIdx.x * blockDim.x + threadIdx.x; i < n4; i += stride) {
        float4 v = out[i];
        v.x = fmaxf(v.x, 0.f); v.y = fmaxf(v.y, 0.f);
        v.z = fmaxf(v.z, 0.f); v.w = fmaxf(v.w, 0.f);
        out[i] = v;
    }
}

extern "C" void kernel_launch(void* const* d_in, const int* in_sizes, int n_in,
                              void* d_out, int out_size, void* d_ws, size_t ws_size,
                              hipStream_t stream) {
    const float* x = (const float*)d_in[0];
    const void* ei = d_in[1];
    const int D = 128;
    const int n = in_sizes[0] / D;   // 50000
    const int E = in_sizes[1] / 2;   // 600000

    char* ws = (char*)d_ws;
    size_t off = 0;
    auto alloc = [&](size_t bytes) {
        char* p = ws + off;
        off += (bytes + 255) & ~(size_t)255;
        return p;
    };
    auto al = [](size_t b) { return (b + 255) & ~(size_t)255; };

    const int nb = (n + 127) / 128;                  // 391 buckets
    const int CH = (E + SORTB - 1) / SORTB;          // 4688
    const size_t szCur  = al((size_t)nb * 4);
    const size_t szDinv = al((size_t)n * 4);
    const size_t szBkt  = al((size_t)nb * BCAP * 4); // 3.2MB
    const size_t szXb   = al((size_t)n * D * 2);     // 12.8MB
    const size_t needS  = szCur + szDinv + szBkt + szXb;

    if (n <= 65536 && CH <= CHUNKMAX && nb <= NBP && ws_size >= needS) {
        int*   cursor = (int*)alloc(szCur);
        float* dinv   = (float*)alloc(szDinv);
        unsigned int* buckets = (unsigned int*)alloc(szBkt);
        unsigned short* xb    = (unsigned short*)alloc(szXb);

        k_zero_cur<<<1, 512, 0, stream>>>(cursor, nb);
        const int nconv = n * D / 8;  // 800000
        const int grid1 = SORTB + (nconv + 255) / 256;
        k_sort_conv<<<grid1, 256, 0, stream>>>(ei, cursor, buckets, x, xb, E, n, CH, nconv);
        k_dinv<<<nb, 128, 0, stream>>>(cursor, buckets, dinv, n);
        k_gather<<<nb * 8, 256, 0, stream>>>(buckets, cursor, xb, dinv, (float*)d_out, n);
        return;
    }

    // direct fallback
    auto needD = [&](int c) { return al((size_t)n * 4) + al((size_t)n * c * 4); };
    if (ws_size >= needD(48)) {
        int c = (ws_size >= needD(64)) ? 64 : 48;
        int* cnt   = (int*)alloc((size_t)n * 4);
        int* edges = (int*)alloc((size_t)n * c * 4);
        k_zero<<<(n / 4 + 255) / 256, 256, 0, stream>>>((int4*)cnt, n / 4);
        k_fill_direct<<<2048, 256, 0, stream>>>(ei, cnt, edges, E, c);
        k_gather_pad<<<(n + 7) / 8, 256, 0, stream>>>(x, edges, cnt, (float*)d_out, n, c);
        return;
    }

    // last resort: atomic scatter
    float* deg = (float*)alloc((size_t)n * 4);
    hipMemsetAsync(deg, 0, (size_t)n * sizeof(float), stream);
    hipMemsetAsync(d_out, 0, (size_t)out_size * sizeof(float), stream);
    k_deg_simple<<<2048, 256, 0, stream>>>(ei, deg, E);
    k_dinv_simple<<<(n + 255) / 256, 256, 0, stream>>>(deg, n);
    k_scatter_atomic<<<4096, 256, 0, stream>>>(x, ei, deg, (float*)d_out, E);
    k_relu4<<<2048, 256, 0, stream>>>((float4*)d_out, out_size / 4);
}